// Round 1
// baseline (513.540 us; speedup 1.0000x reference)
//
#include <hip/hip_runtime.h>
#include <hip/hip_bf16.h>

#define BB 32
#define NN 1024
#define MM 1024
#define DD 128

typedef __bf16 bf16;
typedef bf16 bf16x8 __attribute__((ext_vector_type(8)));
typedef bf16 bf16x4 __attribute__((ext_vector_type(4)));
typedef float f32x4 __attribute__((ext_vector_type(4)));

#define LOG2E 1.4426950408889634f
#define LN2   0.6931471805599453f
#define ESHIFT 30.5f
#define ESHIFT_C 5.6757e-14f   // exp(-30.5)

__device__ __forceinline__ bf16x8 ld8(const bf16* p) {
    return *reinterpret_cast<const bf16x8*>(p);
}

__device__ __forceinline__ bf16x8 cvt8(const float* p) {
    float4 a = reinterpret_cast<const float4*>(p)[0];
    float4 c = reinterpret_cast<const float4*>(p)[1];
    bf16x8 r;
    r[0]=(bf16)a.x; r[1]=(bf16)a.y; r[2]=(bf16)a.z; r[3]=(bf16)a.w;
    r[4]=(bf16)c.x; r[5]=(bf16)c.y; r[6]=(bf16)c.z; r[7]=(bf16)c.w;
    return r;
}

// ---------- prep: fp32 -> bf16 straight convert ----------
__global__ void k_convert(const float* __restrict__ src, bf16* __restrict__ dst) {
    int i = blockIdx.x * 256 + threadIdx.x;
    float4 v = reinterpret_cast<const float4*>(src)[i];
    bf16x4 o; o[0]=(bf16)v.x; o[1]=(bf16)v.y; o[2]=(bf16)v.z; o[3]=(bf16)v.w;
    reinterpret_cast<bf16x4*>(dst)[i] = o;
}

// ---------- prep: [B][R][C] fp32 -> [B][C][R] bf16 ----------
__global__ void k_transpose(const float* __restrict__ src, bf16* __restrict__ dst,
                            int R, int C) {
    __shared__ float tile[32][33];
    int b = blockIdx.z;
    int c0 = blockIdx.x * 32, r0 = blockIdx.y * 32;
    const float* s = src + (size_t)b * R * C;
    bf16* d = dst + (size_t)b * R * C;
    int tx = threadIdx.x, ty = threadIdx.y;
#pragma unroll
    for (int j = 0; j < 4; ++j)
        tile[ty + j*8][tx] = s[(size_t)(r0 + ty + j*8) * C + c0 + tx];
    __syncthreads();
#pragma unroll
    for (int j = 0; j < 4; ++j)
        d[(size_t)(c0 + ty + j*8) * R + r0 + tx] = (bf16)tile[tx][ty + j*8];
}

// ---------- coeff: Xc = Xs * tanh(W @ A_w^T + A_b), bf16 out ----------
__global__ __launch_bounds__(256) void k_coeff(
    const float* __restrict__ Xs, const float* __restrict__ W,
    const float* __restrict__ Aw, const float* __restrict__ Ab,
    bf16* __restrict__ Xc) {
    int ntile = blockIdx.x, b = blockIdx.y;
    int tid = threadIdx.x;
    int w = tid >> 6, lane = tid & 63, quad = lane >> 4, l16 = lane & 15;
    int nbase = ntile * 64 + w * 16;

    f32x4 accZ[8];
#pragma unroll
    for (int ef = 0; ef < 8; ++ef) accZ[ef] = {0.f, 0.f, 0.f, 0.f};

    const float* Wb = W + ((size_t)b * NN + nbase + l16) * DD;
#pragma unroll
    for (int ks = 0; ks < 4; ++ks) {
        bf16x8 aW = cvt8(Wb + ks * 32 + quad * 8);
#pragma unroll
        for (int ef = 0; ef < 8; ++ef) {
            bf16x8 bA = cvt8(Aw + (size_t)(ef * 16 + l16) * DD + ks * 32 + quad * 8);
            accZ[ef] = __builtin_amdgcn_mfma_f32_16x16x32_bf16(aW, bA, accZ[ef], 0, 0, 0);
        }
    }
#pragma unroll
    for (int ef = 0; ef < 8; ++ef) {
        float ab = Ab[ef * 16 + l16];
#pragma unroll
        for (int r = 0; r < 4; ++r) {
            float z = accZ[ef][r] + ab;
            z = fminf(fmaxf(z, -12.f), 12.f);
            float t = __builtin_amdgcn_exp2f(z * (2.f * LOG2E));
            float c = (t - 1.f) / (t + 1.f);
            int n = nbase + quad * 4 + r;
            size_t idx = ((size_t)b * NN + n) * DD + ef * 16 + l16;
            Xc[idx] = (bf16)(Xs[idx] * c);
        }
    }
}

// ---------- main pass 1: s, rowsum->attention_x, colsum ----------
__global__ __launch_bounds__(256) void k_main_x(
    const bf16* __restrict__ Xc, const bf16* __restrict__ Ysb,
    const bf16* __restrict__ YsT, float* __restrict__ colsum,
    float* __restrict__ out_x, float* __restrict__ out_s) {
    __shared__ __align__(16) bf16 Et[4][16][72];
    __shared__ float csum[MM];
    int ntile = blockIdx.x, b = blockIdx.y;
    int tid = threadIdx.x;
    int w = tid >> 6, lane = tid & 63, quad = lane >> 4, l16 = lane & 15;
    int nbase = ntile * 64 + w * 16;

    for (int i = tid; i < MM; i += 256) csum[i] = 0.f;
    __syncthreads();

    // persistent A fragments: this wave's 16 rows of Xc
    const bf16* XcRow = Xc + ((size_t)b * NN + nbase + l16) * DD;
    bf16x8 aX[4];
#pragma unroll
    for (int ks = 0; ks < 4; ++ks) aX[ks] = ld8(XcRow + ks * 32 + quad * 8);

    f32x4 accU[8];
#pragma unroll
    for (int df = 0; df < 8; ++df) accU[df] = {0.f, 0.f, 0.f, 0.f};
    float rowsum[4] = {0.f, 0.f, 0.f, 0.f};

    const bf16* Ysb_b = Ysb + (size_t)b * MM * DD;
    const bf16* YsT_b = YsT + (size_t)b * DD * MM;
    float* s_b = out_s + (size_t)b * NN * MM;

    for (int mt = 0; mt < 16; ++mt) {
        f32x4 accS[4];
#pragma unroll
        for (int mf = 0; mf < 4; ++mf) accS[mf] = {0.f, 0.f, 0.f, 0.f};
#pragma unroll
        for (int ks = 0; ks < 4; ++ks) {
#pragma unroll
            for (int mf = 0; mf < 4; ++mf) {
                bf16x8 bY = ld8(Ysb_b + (size_t)(mt * 64 + mf * 16 + l16) * DD + ks * 32 + quad * 8);
                accS[mf] = __builtin_amdgcn_mfma_f32_16x16x32_bf16(aX[ks], bY, accS[mf], 0, 0, 0);
            }
        }
        // epilogue: s out, E = exp(s - 30.5) exactly, rowsum/colsum
#pragma unroll
        for (int mf = 0; mf < 4; ++mf) {
            float colp = 0.f;
#pragma unroll
            for (int r = 0; r < 4; ++r) {
                float x = accS[mf][r];
                float ax = fabsf(x);
                float sp = fmaxf(x, 0.f) +
                           LN2 * __builtin_amdgcn_logf(1.f + __builtin_amdgcn_exp2f(-ax * LOG2E));
                int n = nbase + quad * 4 + r;
                s_b[(size_t)n * MM + mt * 64 + mf * 16 + l16] = sp - 0.5f;
                float E = __builtin_amdgcn_exp2f((x - ESHIFT) * LOG2E) + ESHIFT_C;
                bf16 Eb = (bf16)E;
                float Ef = (float)Eb;
                rowsum[r] += Ef;
                colp += Ef;
                Et[w][quad * 4 + r][mf * 16 + l16] = Eb;
            }
            colp += __shfl_xor(colp, 16);
            colp += __shfl_xor(colp, 32);
            if (lane < 16) atomicAdd(&csum[mt * 64 + mf * 16 + lane], colp);
        }
        // GEMM2: U += E @ Ys_tile (wave-private Et, no barrier needed)
#pragma unroll
        for (int k2 = 0; k2 < 2; ++k2) {
            bf16x8 aE = *reinterpret_cast<const bf16x8*>(&Et[w][l16][k2 * 32 + quad * 8]);
#pragma unroll
            for (int df = 0; df < 8; ++df) {
                bf16x8 bT = ld8(YsT_b + (size_t)(df * 16 + l16) * MM + mt * 64 + k2 * 32 + quad * 8);
                accU[df] = __builtin_amdgcn_mfma_f32_16x16x32_bf16(aE, bT, accU[df], 0, 0, 0);
            }
        }
    }
    // rowsum butterfly across the 16 column-lanes of each quad
#pragma unroll
    for (int r = 0; r < 4; ++r) {
        float rs = rowsum[r];
        rs += __shfl_xor(rs, 1); rs += __shfl_xor(rs, 2);
        rs += __shfl_xor(rs, 4); rs += __shfl_xor(rs, 8);
        rowsum[r] = 1.f / rs;
    }
#pragma unroll
    for (int df = 0; df < 8; ++df) {
#pragma unroll
        for (int r = 0; r < 4; ++r) {
            int n = nbase + quad * 4 + r;
            out_x[((size_t)b * NN + n) * DD + df * 16 + l16] = accU[df][r] * rowsum[r];
        }
    }
    __syncthreads();
    for (int i = tid; i < MM; i += 256)
        atomicAdd(&colsum[(size_t)b * MM + i], csum[i]);
}

// ---------- main pass 2: attention_y (recompute E, scale by colsum) ----------
__global__ __launch_bounds__(256) void k_main_y(
    const bf16* __restrict__ Ysb, const bf16* __restrict__ Xc,
    const bf16* __restrict__ XsT, const float* __restrict__ colsum,
    float* __restrict__ out_y) {
    __shared__ __align__(16) bf16 Et[4][16][72];
    int mtile = blockIdx.x, b = blockIdx.y;
    int tid = threadIdx.x;
    int w = tid >> 6, lane = tid & 63, quad = lane >> 4, l16 = lane & 15;
    int mbase = mtile * 64 + w * 16;

    const bf16* YRow = Ysb + ((size_t)b * MM + mbase + l16) * DD;
    bf16x8 aY[4];
#pragma unroll
    for (int ks = 0; ks < 4; ++ks) aY[ks] = ld8(YRow + ks * 32 + quad * 8);

    f32x4 accV[8];
#pragma unroll
    for (int df = 0; df < 8; ++df) accV[df] = {0.f, 0.f, 0.f, 0.f};

    const bf16* Xc_b = Xc + (size_t)b * NN * DD;
    const bf16* XsT_b = XsT + (size_t)b * DD * NN;

    for (int nt = 0; nt < 16; ++nt) {
        f32x4 accS[4];
#pragma unroll
        for (int nf = 0; nf < 4; ++nf) accS[nf] = {0.f, 0.f, 0.f, 0.f};
#pragma unroll
        for (int ks = 0; ks < 4; ++ks) {
#pragma unroll
            for (int nf = 0; nf < 4; ++nf) {
                bf16x8 bX = ld8(Xc_b + (size_t)(nt * 64 + nf * 16 + l16) * DD + ks * 32 + quad * 8);
                accS[nf] = __builtin_amdgcn_mfma_f32_16x16x32_bf16(aY[ks], bX, accS[nf], 0, 0, 0);
            }
        }
#pragma unroll
        for (int nf = 0; nf < 4; ++nf) {
#pragma unroll
            for (int r = 0; r < 4; ++r) {
                float x = accS[nf][r];   // x^T[m][n] == x[n][m]
                float E = __builtin_amdgcn_exp2f((x - ESHIFT) * LOG2E) + ESHIFT_C;
                Et[w][quad * 4 + r][nf * 16 + l16] = (bf16)E;
            }
        }
#pragma unroll
        for (int k2 = 0; k2 < 2; ++k2) {
            bf16x8 aE = *reinterpret_cast<const bf16x8*>(&Et[w][l16][k2 * 32 + quad * 8]);
#pragma unroll
            for (int df = 0; df < 8; ++df) {
                bf16x8 bT = ld8(XsT_b + (size_t)(df * 16 + l16) * NN + nt * 64 + k2 * 32 + quad * 8);
                accV[df] = __builtin_amdgcn_mfma_f32_16x16x32_bf16(aE, bT, accV[df], 0, 0, 0);
            }
        }
    }
    float inv[4];
#pragma unroll
    for (int r = 0; r < 4; ++r)
        inv[r] = 1.f / colsum[(size_t)b * MM + mbase + quad * 4 + r];
#pragma unroll
    for (int df = 0; df < 8; ++df) {
#pragma unroll
        for (int r = 0; r < 4; ++r) {
            int m = mbase + quad * 4 + r;
            out_y[((size_t)b * MM + m) * DD + df * 16 + l16] = accV[df][r] * inv[r];
        }
    }
}

extern "C" void kernel_launch(void* const* d_in, const int* in_sizes, int n_in,
                              void* d_out, int out_size, void* d_ws, size_t ws_size,
                              hipStream_t stream) {
    const float* Xs = (const float*)d_in[0];
    const float* Ys = (const float*)d_in[1];
    const float* W  = (const float*)d_in[2];
    const float* Aw = (const float*)d_in[3];
    const float* Ab = (const float*)d_in[4];

    char* ws = (char*)d_ws;
    bf16*  Xc     = (bf16*)(ws);                 //  8 MB
    bf16*  Ysb    = (bf16*)(ws + 8388608);       //  8 MB
    bf16*  YsT    = (bf16*)(ws + 16777216);      //  8 MB
    bf16*  XsT    = (bf16*)(ws + 25165824);      //  8 MB
    float* colsum = (float*)(ws + 33554432);     // 128 KB

    float* out_x = (float*)d_out;
    float* out_y = out_x + (size_t)BB * NN * DD;
    float* out_s = out_y + (size_t)BB * MM * DD;

    hipMemsetAsync(colsum, 0, (size_t)BB * MM * sizeof(float), stream);

    k_convert<<<dim3(BB * MM * DD / 4 / 256), 256, 0, stream>>>(Ys, Ysb);
    k_transpose<<<dim3(DD / 32, MM / 32, BB), dim3(32, 8), 0, stream>>>(Ys, YsT, MM, DD);
    k_transpose<<<dim3(DD / 32, NN / 32, BB), dim3(32, 8), 0, stream>>>(Xs, XsT, NN, DD);
    k_coeff<<<dim3(NN / 64, BB), 256, 0, stream>>>(Xs, W, Aw, Ab, Xc);
    k_main_x<<<dim3(NN / 64, BB), 256, 0, stream>>>(Xc, Ysb, YsT, colsum, out_x, out_s);
    k_main_y<<<dim3(MM / 64, BB), 256, 0, stream>>>(Ysb, Xc, XsT, colsum, out_y);
}

// Round 2
// 465.723 us; speedup vs baseline: 1.1027x; 1.1027x over previous
//
#include <hip/hip_runtime.h>
#include <hip/hip_bf16.h>

#define BB 32
#define NN 1024
#define MM 1024
#define DD 128

typedef __bf16 bf16;
typedef bf16 bf16x8 __attribute__((ext_vector_type(8)));
typedef bf16 bf16x4 __attribute__((ext_vector_type(4)));
typedef float f32x4 __attribute__((ext_vector_type(4)));

#define LOG2E 1.4426950408889634f
#define LN2   0.6931471805599453f
#define ESHIFT 30.5f
#define ESHIFT_C 5.6757e-14f   // exp(-30.5)

__device__ __forceinline__ bf16x8 ld8(const bf16* p) {
    return *reinterpret_cast<const bf16x8*>(p);
}

__device__ __forceinline__ bf16x8 cvt8(const float* p) {
    float4 a = reinterpret_cast<const float4*>(p)[0];
    float4 c = reinterpret_cast<const float4*>(p)[1];
    bf16x8 r;
    r[0]=(bf16)a.x; r[1]=(bf16)a.y; r[2]=(bf16)a.z; r[3]=(bf16)a.w;
    r[4]=(bf16)c.x; r[5]=(bf16)c.y; r[6]=(bf16)c.z; r[7]=(bf16)c.w;
    return r;
}

// ---------- prep: fp32 -> bf16 straight convert ----------
__global__ void k_convert(const float* __restrict__ src, bf16* __restrict__ dst) {
    int i = blockIdx.x * 256 + threadIdx.x;
    float4 v = reinterpret_cast<const float4*>(src)[i];
    bf16x4 o; o[0]=(bf16)v.x; o[1]=(bf16)v.y; o[2]=(bf16)v.z; o[3]=(bf16)v.w;
    reinterpret_cast<bf16x4*>(dst)[i] = o;
}

// ---------- prep: [B][R][C] fp32 -> [B][C][R] bf16 ----------
__global__ void k_transpose(const float* __restrict__ src, bf16* __restrict__ dst,
                            int R, int C) {
    __shared__ float tile[32][33];
    int b = blockIdx.z;
    int c0 = blockIdx.x * 32, r0 = blockIdx.y * 32;
    const float* s = src + (size_t)b * R * C;
    bf16* d = dst + (size_t)b * R * C;
    int tx = threadIdx.x, ty = threadIdx.y;
#pragma unroll
    for (int j = 0; j < 4; ++j)
        tile[ty + j*8][tx] = s[(size_t)(r0 + ty + j*8) * C + c0 + tx];
    __syncthreads();
#pragma unroll
    for (int j = 0; j < 4; ++j)
        d[(size_t)(c0 + ty + j*8) * R + r0 + tx] = (bf16)tile[tx][ty + j*8];
}

// ---------- coeff: Xc = Xs * tanh(W @ A_w^T + A_b), bf16 out ----------
__global__ __launch_bounds__(256) void k_coeff(
    const float* __restrict__ Xs, const float* __restrict__ W,
    const float* __restrict__ Aw, const float* __restrict__ Ab,
    bf16* __restrict__ Xc) {
    int ntile = blockIdx.x, b = blockIdx.y;
    int tid = threadIdx.x;
    int w = tid >> 6, lane = tid & 63, quad = lane >> 4, l16 = lane & 15;
    int nbase = ntile * 64 + w * 16;

    f32x4 accZ[8];
#pragma unroll
    for (int ef = 0; ef < 8; ++ef) accZ[ef] = {0.f, 0.f, 0.f, 0.f};

    const float* Wb = W + ((size_t)b * NN + nbase + l16) * DD;
#pragma unroll
    for (int ks = 0; ks < 4; ++ks) {
        bf16x8 aW = cvt8(Wb + ks * 32 + quad * 8);
#pragma unroll
        for (int ef = 0; ef < 8; ++ef) {
            bf16x8 bA = cvt8(Aw + (size_t)(ef * 16 + l16) * DD + ks * 32 + quad * 8);
            accZ[ef] = __builtin_amdgcn_mfma_f32_16x16x32_bf16(aW, bA, accZ[ef], 0, 0, 0);
        }
    }
#pragma unroll
    for (int ef = 0; ef < 8; ++ef) {
        float ab = Ab[ef * 16 + l16];
#pragma unroll
        for (int r = 0; r < 4; ++r) {
            float z = accZ[ef][r] + ab;
            z = fminf(fmaxf(z, -12.f), 12.f);
            float t = __builtin_amdgcn_exp2f(z * (2.f * LOG2E));
            float c = (t - 1.f) / (t + 1.f);
            int n = nbase + quad * 4 + r;
            size_t idx = ((size_t)b * NN + n) * DD + ef * 16 + l16;
            Xc[idx] = (bf16)(Xs[idx] * c);
        }
    }
}

// ---------- main pass 1: s, rowsum->attention_x, colsum ----------
// Block: 32 rows of n. 4 waves = (rowgrp 0/1) x (m-half 0/1); each wave does
// 8 of the 16 m-tiles; partial accU / rowsum merge through LDS.
__global__ __launch_bounds__(256, 4) void k_main_x(
    const bf16* __restrict__ Xc, const bf16* __restrict__ Ysb,
    const bf16* __restrict__ YsT, float* __restrict__ colsum,
    float* __restrict__ out_x, float* __restrict__ out_s) {
    __shared__ __align__(16) float Uacc[2][32][128];   // 32 KB; Et overlays front
    __shared__ float csum[MM];                          // 4 KB
    __shared__ float rsum[32];
    bf16 (*Et)[16][72] = reinterpret_cast<bf16(*)[16][72]>(&Uacc[0][0][0]);

    int ntile = blockIdx.x, b = blockIdx.y;
    int tid = threadIdx.x;
    int w = tid >> 6, lane = tid & 63, quad = lane >> 4, l16 = lane & 15;
    int rowgrp = w >> 1, half = w & 1;
    int nbase = ntile * 32 + rowgrp * 16;

    for (int i = tid; i < MM; i += 256) csum[i] = 0.f;
    if (tid < 32) rsum[tid] = 0.f;
    __syncthreads();

    // persistent A fragments: this wave's 16 rows of Xc
    const bf16* XcRow = Xc + ((size_t)b * NN + nbase + l16) * DD;
    bf16x8 aX[4];
#pragma unroll
    for (int ks = 0; ks < 4; ++ks) aX[ks] = ld8(XcRow + ks * 32 + quad * 8);

    f32x4 accU[8];
#pragma unroll
    for (int df = 0; df < 8; ++df) accU[df] = {0.f, 0.f, 0.f, 0.f};
    float rowsum[4] = {0.f, 0.f, 0.f, 0.f};

    const bf16* Ysb_b = Ysb + (size_t)b * MM * DD;
    const bf16* YsT_b = YsT + (size_t)b * DD * MM;
    float* s_b = out_s + (size_t)b * NN * MM;

    for (int mi = 0; mi < 8; ++mi) {
        int mt = half * 8 + mi;
        f32x4 accS[4];
#pragma unroll
        for (int mf = 0; mf < 4; ++mf) accS[mf] = {0.f, 0.f, 0.f, 0.f};
#pragma unroll
        for (int ks = 0; ks < 4; ++ks) {
#pragma unroll
            for (int mf = 0; mf < 4; ++mf) {
                bf16x8 bY = ld8(Ysb_b + (size_t)(mt * 64 + mf * 16 + l16) * DD + ks * 32 + quad * 8);
                accS[mf] = __builtin_amdgcn_mfma_f32_16x16x32_bf16(aX[ks], bY, accS[mf], 0, 0, 0);
            }
        }
        // epilogue: s out, E = exp(s - 30.5) exactly, rowsum/colsum
#pragma unroll
        for (int mf = 0; mf < 4; ++mf) {
            float colp = 0.f;
#pragma unroll
            for (int r = 0; r < 4; ++r) {
                float x = accS[mf][r];
                float ax = fabsf(x);
                float sp = fmaxf(x, 0.f) +
                           LN2 * __builtin_amdgcn_logf(1.f + __builtin_amdgcn_exp2f(-ax * LOG2E));
                int n = nbase + quad * 4 + r;
                s_b[(size_t)n * MM + mt * 64 + mf * 16 + l16] = sp - 0.5f;
                float E = __builtin_amdgcn_exp2f((x - ESHIFT) * LOG2E) + ESHIFT_C;
                bf16 Eb = (bf16)E;
                float Ef = (float)Eb;
                rowsum[r] += Ef;
                colp += Ef;
                Et[w][quad * 4 + r][mf * 16 + l16] = Eb;
            }
            colp += __shfl_xor(colp, 16);
            colp += __shfl_xor(colp, 32);
            if (lane < 16) atomicAdd(&csum[mt * 64 + mf * 16 + lane], colp);
        }
        // GEMM2: U += E @ Ys_tile (wave-private Et, no barrier needed)
#pragma unroll
        for (int k2 = 0; k2 < 2; ++k2) {
            bf16x8 aE = *reinterpret_cast<const bf16x8*>(&Et[w][l16][k2 * 32 + quad * 8]);
#pragma unroll
            for (int df = 0; df < 8; ++df) {
                bf16x8 bT = ld8(YsT_b + (size_t)(df * 16 + l16) * MM + mt * 64 + k2 * 32 + quad * 8);
                accU[df] = __builtin_amdgcn_mfma_f32_16x16x32_bf16(aE, bT, accU[df], 0, 0, 0);
            }
        }
    }
    // partial rowsum: butterfly across the 16 column-lanes, one atomic per row
#pragma unroll
    for (int r = 0; r < 4; ++r) {
        float rs = rowsum[r];
        rs += __shfl_xor(rs, 1); rs += __shfl_xor(rs, 2);
        rs += __shfl_xor(rs, 4); rs += __shfl_xor(rs, 8);
        if (l16 == 0) atomicAdd(&rsum[rowgrp * 16 + quad * 4 + r], rs);
    }
    __syncthreads();   // Et dead beyond here; rsum/csum complete
    // store partial accU into the (overlaid) merge buffer
#pragma unroll
    for (int df = 0; df < 8; ++df) {
#pragma unroll
        for (int r = 0; r < 4; ++r)
            Uacc[half][rowgrp * 16 + quad * 4 + r][df * 16 + l16] = accU[df][r];
    }
    __syncthreads();
    // merge halves, normalize, write out_x
    for (int i = tid; i < 32 * 128; i += 256) {
        int row = i >> 7, col = i & 127;
        float v = (Uacc[0][row][col] + Uacc[1][row][col]) / rsum[row];
        out_x[((size_t)b * NN + ntile * 32 + row) * DD + col] = v;
    }
    // flush colsum partials to global
    for (int i = tid; i < MM; i += 256)
        atomicAdd(&colsum[(size_t)b * MM + i], csum[i]);
}

// ---------- main pass 2: attention_y (recompute E, scale by colsum) ----------
// Block: 32 rows of m. 4 waves = (rowgrp 0/1) x (n-half 0/1).
__global__ __launch_bounds__(256, 4) void k_main_y(
    const bf16* __restrict__ Ysb, const bf16* __restrict__ Xc,
    const bf16* __restrict__ XsT, const float* __restrict__ colsum,
    float* __restrict__ out_y) {
    __shared__ __align__(16) float Vacc[2][32][128];   // 32 KB; Et overlays front
    bf16 (*Et)[16][72] = reinterpret_cast<bf16(*)[16][72]>(&Vacc[0][0][0]);

    int mtile = blockIdx.x, b = blockIdx.y;
    int tid = threadIdx.x;
    int w = tid >> 6, lane = tid & 63, quad = lane >> 4, l16 = lane & 15;
    int rowgrp = w >> 1, half = w & 1;
    int mbase = mtile * 32 + rowgrp * 16;

    const bf16* YRow = Ysb + ((size_t)b * MM + mbase + l16) * DD;
    bf16x8 aY[4];
#pragma unroll
    for (int ks = 0; ks < 4; ++ks) aY[ks] = ld8(YRow + ks * 32 + quad * 8);

    f32x4 accV[8];
#pragma unroll
    for (int df = 0; df < 8; ++df) accV[df] = {0.f, 0.f, 0.f, 0.f};

    const bf16* Xc_b = Xc + (size_t)b * NN * DD;
    const bf16* XsT_b = XsT + (size_t)b * DD * NN;

    for (int ni = 0; ni < 8; ++ni) {
        int nt = half * 8 + ni;
        f32x4 accS[4];
#pragma unroll
        for (int nf = 0; nf < 4; ++nf) accS[nf] = {0.f, 0.f, 0.f, 0.f};
#pragma unroll
        for (int ks = 0; ks < 4; ++ks) {
#pragma unroll
            for (int nf = 0; nf < 4; ++nf) {
                bf16x8 bX = ld8(Xc_b + (size_t)(nt * 64 + nf * 16 + l16) * DD + ks * 32 + quad * 8);
                accS[nf] = __builtin_amdgcn_mfma_f32_16x16x32_bf16(aY[ks], bX, accS[nf], 0, 0, 0);
            }
        }
#pragma unroll
        for (int nf = 0; nf < 4; ++nf) {
#pragma unroll
            for (int r = 0; r < 4; ++r) {
                float x = accS[nf][r];   // s^T[m][n] == s[n][m]
                float E = __builtin_amdgcn_exp2f((x - ESHIFT) * LOG2E) + ESHIFT_C;
                Et[w][quad * 4 + r][nf * 16 + l16] = (bf16)E;
            }
        }
#pragma unroll
        for (int k2 = 0; k2 < 2; ++k2) {
            bf16x8 aE = *reinterpret_cast<const bf16x8*>(&Et[w][l16][k2 * 32 + quad * 8]);
#pragma unroll
            for (int df = 0; df < 8; ++df) {
                bf16x8 bT = ld8(XsT_b + (size_t)(df * 16 + l16) * NN + nt * 64 + k2 * 32 + quad * 8);
                accV[df] = __builtin_amdgcn_mfma_f32_16x16x32_bf16(aE, bT, accV[df], 0, 0, 0);
            }
        }
    }
    __syncthreads();   // all waves done with Et
#pragma unroll
    for (int df = 0; df < 8; ++df) {
#pragma unroll
        for (int r = 0; r < 4; ++r)
            Vacc[half][rowgrp * 16 + quad * 4 + r][df * 16 + l16] = accV[df][r];
    }
    __syncthreads();
    for (int i = tid; i < 32 * 128; i += 256) {
        int row = i >> 7, col = i & 127;
        int m = mtile * 32 + row;
        float v = (Vacc[0][row][col] + Vacc[1][row][col]) / colsum[(size_t)b * MM + m];
        out_y[((size_t)b * MM + m) * DD + col] = v;
    }
}

extern "C" void kernel_launch(void* const* d_in, const int* in_sizes, int n_in,
                              void* d_out, int out_size, void* d_ws, size_t ws_size,
                              hipStream_t stream) {
    const float* Xs = (const float*)d_in[0];
    const float* Ys = (const float*)d_in[1];
    const float* W  = (const float*)d_in[2];
    const float* Aw = (const float*)d_in[3];
    const float* Ab = (const float*)d_in[4];

    char* ws = (char*)d_ws;
    bf16*  Xc     = (bf16*)(ws);                 //  8 MB
    bf16*  Ysb    = (bf16*)(ws + 8388608);       //  8 MB
    bf16*  YsT    = (bf16*)(ws + 16777216);      //  8 MB
    bf16*  XsT    = (bf16*)(ws + 25165824);      //  8 MB
    float* colsum = (float*)(ws + 33554432);     // 128 KB

    float* out_x = (float*)d_out;
    float* out_y = out_x + (size_t)BB * NN * DD;
    float* out_s = out_y + (size_t)BB * MM * DD;

    hipMemsetAsync(colsum, 0, (size_t)BB * MM * sizeof(float), stream);

    k_convert<<<dim3(BB * MM * DD / 4 / 256), 256, 0, stream>>>(Ys, Ysb);
    k_transpose<<<dim3(DD / 32, MM / 32, BB), dim3(32, 8), 0, stream>>>(Ys, YsT, MM, DD);
    k_transpose<<<dim3(DD / 32, NN / 32, BB), dim3(32, 8), 0, stream>>>(Xs, XsT, NN, DD);
    k_coeff<<<dim3(NN / 64, BB), 256, 0, stream>>>(Xs, W, Aw, Ab, Xc);
    k_main_x<<<dim3(NN / 32, BB), 256, 0, stream>>>(Xc, Ysb, YsT, colsum, out_x, out_s);
    k_main_y<<<dim3(MM / 32, BB), 256, 0, stream>>>(Ysb, Xc, XsT, colsum, out_y);
}